// Round 7
// baseline (366.913 us; speedup 1.0000x reference)
//
#include <hip/hip_runtime.h>
#include <math.h>

#define BATCH 4
#define CH    96
#define HH    48
#define WW    48
#define HWPIX (HH*WW)         // 2304
#define NPIX  (BATCH*HWPIX)   // 9216
#define WIN   13
#define WIN2  169
#define HALF  6
#define TOPK  8
#define NEGV  (-1000000000.0f)

#define WROWS   256           // 16x16 window rows per 4x4 tile
#define WSTRIDE 52            // floats per LDS row: 48 data + 4 pad (bank spread)

// ---------------------------------------------------------------------------
// K1: transpose x (B,C,HW) -> xt (B*HW, C) [xt lives in d_out], + invn
// ---------------------------------------------------------------------------
__global__ __launch_bounds__(256) void k1_prep(
    const float* __restrict__ x, float* __restrict__ xt,
    float* __restrict__ invn)
{
    __shared__ float lds[96][33];
    int bid = blockIdx.x;          // 288 = 4 batches * 72 tiles
    int b   = bid / 72;
    int p0  = (bid % 72) * 32;
    int t   = threadIdx.x;

    #pragma unroll
    for (int it = 0; it < 12; ++it) {
        int e = t + it * 256;
        int c = e >> 5;
        int p = e & 31;
        lds[c][p] = x[(b * CH + c) * HWPIX + p0 + p];
    }
    __syncthreads();

    if (t < 32) {
        float ss = 0.f;
        #pragma unroll
        for (int c = 0; c < CH; ++c) { float v = lds[c][t]; ss += v * v; }
        invn[b * HWPIX + p0 + t] = 1.0f / fmaxf(sqrtf(ss), 1e-12f);
    }

    #pragma unroll
    for (int it = 0; it < 12; ++it) {
        int e = t + it * 256;
        int p = e / 96;
        int c = e - p * 96;
        xt[(b * HWPIX + p0 + p) * CH + c] = lds[c][p];
    }
}

// ---------------------------------------------------------------------------
// K2: LDS-tiled KNN. Block = 4x4 pixel tile, 512 threads (8 waves).
//     Dot loop restructured s-outer/k-inner: no large live arrays -> no spill.
// ---------------------------------------------------------------------------
__global__ __launch_bounds__(512) void k2_knn(
    const float* __restrict__ xt, const float* __restrict__ invn,
    const float* __restrict__ lnw, const float* __restrict__ lnb,
    float* __restrict__ enh)
{
    __shared__ float wt[WROWS * WSTRIDE];   // 53,248 B
    int t    = threadIdx.x;
    int wv   = t >> 6;
    int lane = t & 63;
    // XCD-aware bijective swizzle (576 % 8 == 0)
    int blk  = (blockIdx.x & 7) * 72 + (blockIdx.x >> 3);
    int b    = blk / 144;
    int tid  = blk % 144;
    int ty0  = (tid / 12) * 4;
    int tx0  = (tid % 12) * 4;

    // persistent per-(pixel, slot) state (18 small regs)
    float sim[2][3];
    int   rrow[2][3];
    bool  vld[2][3];
    #pragma unroll
    for (int i = 0; i < 2; ++i) {
        int p  = wv * 2 + i;
        int ly = p >> 2, lx = p & 3;
        #pragma unroll
        for (int k = 0; k < 3; ++k) {
            sim[i][k] = 0.f;
            int n  = lane + 64 * k;
            int dy = n / WIN;
            int dx = n - dy * WIN;
            int wy = ly + dy, wx = lx + dx;
            int r  = wy * 16 + wx;
            rrow[i][k] = (r < 255) ? r : 255;
            int gy = ty0 - 6 + wy, gx = tx0 - 6 + wx;
            vld[i][k] = (n < WIN2) && (gy >= 0) && (gy < HH)
                                   && (gx >= 0) && (gx < WW);
        }
    }

    // two K-halves: stage 48 channels, accumulate partial dots
    #pragma unroll
    for (int h = 0; h < 2; ++h) {
        if (h) __syncthreads();          // prior dots done before restage
        #pragma unroll
        for (int it = 0; it < 6; ++it) {
            int idx = t + it * 512;      // 3072 = 256 rows * 12 float4
            int r   = idx / 12;
            int s   = idx - r * 12;
            int wy  = r >> 4, wx = r & 15;
            int gy  = ty0 - 6 + wy, gx = tx0 - 6 + wx;
            float4 v = make_float4(0.f, 0.f, 0.f, 0.f);
            if (gy >= 0 && gy < HH && gx >= 0 && gx < WW) {
                int q = b * HWPIX + gy * WW + gx;
                float sc = invn[q];
                float4 raw = ((const float4*)(xt + q * CH + h * 48))[s];
                v.x = raw.x * sc; v.y = raw.y * sc;
                v.z = raw.z * sc; v.w = raw.w * sc;
            }
            ((float4*)(wt + r * WSTRIDE))[s] = v;
        }
        __syncthreads();

        #pragma unroll
        for (int i = 0; i < 2; ++i) {
            int p  = wv * 2 + i;
            int ly = p >> 2, lx = p & 3;
            int rown = (ly + 6) * 16 + (lx + 6);
            const float4* ownp = (const float4*)(wt + rown * WSTRIDE);
            const float4* rp0  = (const float4*)(wt + rrow[i][0] * WSTRIDE);
            const float4* rp1  = (const float4*)(wt + rrow[i][1] * WSTRIDE);
            const float4* rp2  = (const float4*)(wt + rrow[i][2] * WSTRIDE);
            // 12 independent accumulators; live set ~35 VGPRs, no arrays
            float a0x=0.f,a0y=0.f,a0z=0.f,a0w=0.f;
            float a1x=0.f,a1y=0.f,a1z=0.f,a1w=0.f;
            float a2x=0.f,a2y=0.f,a2z=0.f,a2w=0.f;
            #pragma unroll
            for (int s = 0; s < 12; ++s) {
                float4 o  = ownp[s];     // wave-uniform -> LDS broadcast
                float4 b0 = rp0[s];
                float4 b1 = rp1[s];
                float4 b2 = rp2[s];
                a0x += o.x*b0.x; a0y += o.y*b0.y; a0z += o.z*b0.z; a0w += o.w*b0.w;
                a1x += o.x*b1.x; a1y += o.y*b1.y; a1z += o.z*b1.z; a1w += o.w*b1.w;
                a2x += o.x*b2.x; a2y += o.y*b2.y; a2z += o.z*b2.z; a2w += o.w*b2.w;
            }
            sim[i][0] += (a0x + a0y) + (a0z + a0w);
            sim[i][1] += (a1x + a1y) + (a1z + a1w);
            sim[i][2] += (a2x + a2y) + (a2z + a2w);
        }
    }

    // finalize per pixel: top-8, softmax, aggregate raw feats, LayerNorm
    #pragma unroll
    for (int i = 0; i < 2; ++i) {
        int p  = wv * 2 + i;
        int ly = p >> 2, lx = p & 3;
        int py = ty0 + ly, px = tx0 + lx;
        int gp = b * HWPIX + py * WW + px;

        float v0 = vld[i][0] ? sim[i][0] : NEGV;
        float v1 = vld[i][1] ? sim[i][1] : NEGV;
        float v2 = vld[i][2] ? sim[i][2] : NEGV;

        float tv[TOPK]; int tn[TOPK];
        #pragma unroll
        for (int r = 0; r < TOPK; ++r) {
            float v = v0; int n = lane;
            if (v1 > v) { v = v1; n = lane + 64; }
            if (v2 > v) { v = v2; n = lane + 128; }
            #pragma unroll
            for (int off = 1; off < 64; off <<= 1) {
                float ov = __shfl_xor(v, off);
                int   on = __shfl_xor(n, off);
                if (ov > v || (ov == v && on < n)) { v = ov; n = on; }
            }
            tv[r] = v; tn[r] = n;
            bool mine = (n & 63) == lane;
            int  kk = n >> 6;
            v0 = (mine && kk == 0) ? -2e9f : v0;
            v1 = (mine && kk == 1) ? -2e9f : v1;
            v2 = (mine && kk == 2) ? -2e9f : v2;
        }

        float wts[TOPK]; int qn[TOPK];
        float wsum = 0.f;
        #pragma unroll
        for (int r = 0; r < TOPK; ++r) {
            float e = expf(tv[r] - tv[0]);
            wts[r] = e; wsum += e;
            int n  = tn[r];
            int dy = n / WIN - HALF;
            int dx = n - (dy + HALF) * WIN - HALF;
            int gy = min(max(py + dy, 0), HH - 1);
            int gx = min(max(px + dx, 0), WW - 1);
            qn[r]  = b * HWPIX + gy * WW + gx;
        }
        float winv = 1.0f / wsum;

        // own raw row + wave-reduced LN stats
        const float* xrow = xt + gp * CH;
        float r1  = xrow[lane];
        float r2v = xrow[64 + (lane & 31)];
        float r2  = (lane < 32) ? r2v : 0.f;
        float s  = r1 + r2;
        float ss = r1 * r1 + r2 * r2;
        #pragma unroll
        for (int off = 1; off < 64; off <<= 1) {
            s  += __shfl_xor(s, off);
            ss += __shfl_xor(ss, off);
        }
        float mu  = s * (1.0f / 96.0f);
        float var = ss * (1.0f / 96.0f) - mu * mu;
        float rsd = rsqrtf(var + 1e-5f);

        float a1 = 0.f, a2 = 0.f;
        #pragma unroll
        for (int r = 0; r < TOPK; ++r) {
            const float* qrow = xt + qn[r] * CH;
            a1 += wts[r] * qrow[lane];
            a2 += wts[r] * qrow[64 + (lane & 31)];
        }
        a1 *= winv; a2 *= winv;

        enh[gp * CH + lane] = a1 + (r1 - mu) * rsd * lnw[lane] + lnb[lane];
        if (lane < 32) {
            int c = 64 + lane;
            enh[gp * CH + c] = a2 + (r2 - mu) * rsd * lnw[c] + lnb[c];
        }
    }
}

// ---------------------------------------------------------------------------
// K3: fused FFN. 8 px per block, 1152 blocks, 256 threads.
// ---------------------------------------------------------------------------
__global__ __launch_bounds__(256) void k3_ffn(
    const float* __restrict__ enh, const float* __restrict__ w1,
    const float* __restrict__ b1, const float* __restrict__ w2,
    const float* __restrict__ b2, float* __restrict__ out)
{
    __shared__ float hl[8][200];    // 6.25 KB, rows 800 B (16B-aligned)
    int g    = blockIdx.x;          // 1152 = 4 batches * 288 tiles
    int b    = g / 288;
    int p0   = (g % 288) * 8;
    int t    = threadIdx.x;
    int wv   = t >> 6;
    int lane = t & 63;
    int pix  = lane & 7;
    int sub  = lane >> 3;           // 0..7
    int grp  = wv * 8 + sub;        // 0..31
    int gp   = b * HWPIX + p0 + pix;

    float4 ereg[24];
    const float4* ev = (const float4*)(enh + gp * CH);
    #pragma unroll
    for (int c4 = 0; c4 < 24; ++c4) ereg[c4] = ev[c4];

    // phase A: 6 hidden units per lane
    const float4* w1v = (const float4*)w1;
    #pragma unroll
    for (int jj = 0; jj < 6; ++jj) {
        int j = grp * 6 + jj;
        float ax = 0.f, ay = 0.f, az = 0.f, aw = 0.f;
        #pragma unroll
        for (int c4 = 0; c4 < 24; ++c4) {
            float4 w4 = w1v[j * 24 + c4];
            ax += ereg[c4].x * w4.x; ay += ereg[c4].y * w4.y;
            az += ereg[c4].z * w4.z; aw += ereg[c4].w * w4.w;
        }
        hl[pix][j] = fmaxf(((ax + ay) + (az + aw)) + b1[j], 0.f);
    }
    __syncthreads();

    // phase B: 3 output channels per lane
    const float4* w2v = (const float4*)w2;
    const float4* hv4 = (const float4*)(&hl[pix][0]);
    float a0 = 0.f, a1 = 0.f, a2 = 0.f;
    int c0 = grp * 3;
    #pragma unroll 6
    for (int j4 = 0; j4 < 48; ++j4) {
        float4 hv = hv4[j4];
        float4 q0 = w2v[(c0 + 0) * 48 + j4];
        float4 q1 = w2v[(c0 + 1) * 48 + j4];
        float4 q2 = w2v[(c0 + 2) * 48 + j4];
        a0 += hv.x*q0.x + hv.y*q0.y + hv.z*q0.z + hv.w*q0.w;
        a1 += hv.x*q1.x + hv.y*q1.y + hv.z*q1.z + hv.w*q1.w;
        a2 += hv.x*q2.x + hv.y*q2.y + hv.z*q2.z + hv.w*q2.w;
    }

    float accs[3] = {a0, a1, a2};
    #pragma unroll
    for (int cc = 0; cc < 3; ++cc) {
        int c = c0 + cc;
        out[(b * CH + c) * HWPIX + p0 + pix] =
            enh[gp * CH + c] + accs[cc] + b2[c];
    }
}

// ---------------------------------------------------------------------------
extern "C" void kernel_launch(void* const* d_in, const int* in_sizes, int n_in,
                              void* d_out, int out_size, void* d_ws, size_t ws_size,
                              hipStream_t stream)
{
    const float* x   = (const float*)d_in[0];
    const float* w1  = (const float*)d_in[1];
    const float* b1  = (const float*)d_in[2];
    const float* w2  = (const float*)d_in[3];
    const float* b2  = (const float*)d_in[4];
    const float* lnw = (const float*)d_in[5];
    const float* lnb = (const float*)d_in[6];
    float* out = (float*)d_out;

    // xt lives in d_out (exactly NPIX*CH floats): k1 writes it, k2 consumes it,
    // k3 then overwrites d_out with the final output (stream-ordered).
    float* xt = out;

    // workspace: enh + invn = 893,952 floats = 3.58 MB
    float* ws   = (float*)d_ws;
    float* enh  = ws;                        // NPIX*96
    float* invn = enh + NPIX * CH;           // NPIX

    hipLaunchKernelGGL(k1_prep, dim3(288), dim3(256), 0, stream,
                       x, xt, invn);
    hipLaunchKernelGGL(k2_knn, dim3(576), dim3(512), 0, stream,
                       xt, invn, lnw, lnb, enh);
    hipLaunchKernelGGL(k3_ffn, dim3(1152), dim3(256), 0, stream,
                       enh, w1, b1, w2, b2, out);
}

// Round 9
// 149.142 us; speedup vs baseline: 2.4602x; 2.4602x over previous
//
#include <hip/hip_runtime.h>
#include <math.h>

#define BATCH 4
#define CH    96
#define HH    48
#define WW    48
#define HWPIX (HH*WW)         // 2304
#define NPIX  (BATCH*HWPIX)   // 9216
#define WIN   13
#define WIN2  169
#define HALF  6
#define TOPK  8
#define NEGV  (-1000000000.0f)

// ---------------------------------------------------------------------------
// K1: transpose x (B,C,HW) -> xt (B*HW, C) [xt lives in d_out], + invn
// ---------------------------------------------------------------------------
__global__ __launch_bounds__(256) void k1_prep(
    const float* __restrict__ x, float* __restrict__ xt,
    float* __restrict__ invn)
{
    __shared__ float lds[96][33];
    int bid = blockIdx.x;          // 288 = 4 batches * 72 tiles
    int b   = bid / 72;
    int p0  = (bid % 72) * 32;
    int t   = threadIdx.x;

    #pragma unroll
    for (int it = 0; it < 12; ++it) {
        int e = t + it * 256;
        int c = e >> 5;
        int p = e & 31;
        lds[c][p] = x[(b * CH + c) * HWPIX + p0 + p];
    }
    __syncthreads();

    if (t < 32) {
        float ss = 0.f;
        #pragma unroll
        for (int c = 0; c < CH; ++c) { float v = lds[c][t]; ss += v * v; }
        invn[b * HWPIX + p0 + t] = 1.0f / fmaxf(sqrtf(ss), 1e-12f);
    }

    #pragma unroll
    for (int it = 0; it < 12; ++it) {
        int e = t + it * 256;
        int p = e / 96;
        int c = e - p * 96;
        xt[(b * HWPIX + p0 + p) * CH + c] = lds[c][p];
    }
}

// ---------------------------------------------------------------------------
// K2: per-pixel (one wave), round-3 proven structure; dot phase restructured
//     for MLP: branchless clamped pointers, 3 loads/iter, 12 accumulators.
// ---------------------------------------------------------------------------
__global__ __launch_bounds__(256) void k2_knn(
    const float* __restrict__ xt, const float* __restrict__ invn,
    const float* __restrict__ lnw, const float* __restrict__ lnb,
    float* __restrict__ enh)
{
    __shared__ float own[4][96];
    int t    = threadIdx.x;
    int wv   = t >> 6;
    int lane = t & 63;
    // XCD-bijective swizzle (2304 % 8 == 0): each XCD gets a contiguous stripe
    int blk  = (blockIdx.x & 7) * 288 + (blockIdx.x >> 3);
    int gp   = blk * 4 + wv;
    int b    = gp / HWPIX;
    int p    = gp - b * HWPIX;
    int py   = p / WW;
    int px   = p - py * WW;

    // stage own feature vector into LDS (broadcast source for dots)
    own[wv][lane] = xt[gp * CH + lane];
    if (lane < 32) own[wv][lane + 64] = xt[gp * CH + lane + 64];
    float inp = invn[gp];
    __syncthreads();

    // neighbor slots: n = lane, lane+64, lane+128; clamped indices, valid mask
    int   q[3];
    bool  ok[3];
    #pragma unroll
    for (int k = 0; k < 3; ++k) {
        int n  = lane + 64 * k;
        int dy = n / WIN - HALF;
        int dx = n - (dy + HALF) * WIN - HALF;
        int ny = py + dy, nx = px + dx;
        ok[k] = (n < WIN2) && (ny >= 0) && (ny < HH) && (nx >= 0) && (nx < WW);
        int cy = min(max(ny, 0), HH - 1);
        int cx = min(max(nx, 0), WW - 1);
        q[k]  = b * HWPIX + cy * WW + cx;
    }
    float in0 = invn[q[0]], in1 = invn[q[1]], in2 = invn[q[2]];

    // interleaved dot products: 3 global loads + 1 LDS broadcast per iter,
    // 12 independent FMA chains.
    const float4* ov  = (const float4*)(own[wv]);
    const float4* np0 = (const float4*)(xt + q[0] * CH);
    const float4* np1 = (const float4*)(xt + q[1] * CH);
    const float4* np2 = (const float4*)(xt + q[2] * CH);
    float a0x=0.f,a0y=0.f,a0z=0.f,a0w=0.f;
    float a1x=0.f,a1y=0.f,a1z=0.f,a1w=0.f;
    float a2x=0.f,a2y=0.f,a2z=0.f,a2w=0.f;
    #pragma unroll 4
    for (int s = 0; s < 24; ++s) {
        float4 o  = ov[s];
        float4 b0 = np0[s];
        float4 b1 = np1[s];
        float4 b2 = np2[s];
        a0x += o.x*b0.x; a0y += o.y*b0.y; a0z += o.z*b0.z; a0w += o.w*b0.w;
        a1x += o.x*b1.x; a1y += o.y*b1.y; a1z += o.z*b1.z; a1w += o.w*b1.w;
        a2x += o.x*b2.x; a2y += o.y*b2.y; a2z += o.z*b2.z; a2w += o.w*b2.w;
    }
    float v0 = ok[0] ? ((a0x+a0y)+(a0z+a0w)) * inp * in0 : NEGV;
    float v1 = ok[1] ? ((a1x+a1y)+(a1z+a1w)) * inp * in1 : NEGV;
    float v2 = ok[2] ? ((a2x+a2y)+(a2z+a2w)) * inp * in2 : NEGV;

    // iterative top-8 with lax.top_k tie-breaking (equal value -> lower index)
    float tv[TOPK]; int tn[TOPK];
    #pragma unroll
    for (int r = 0; r < TOPK; ++r) {
        float v = v0; int n = lane;
        if (v1 > v) { v = v1; n = lane + 64; }
        if (v2 > v) { v = v2; n = lane + 128; }
        #pragma unroll
        for (int off = 1; off < 64; off <<= 1) {
            float ov2 = __shfl_xor(v, off);
            int   on  = __shfl_xor(n, off);
            if (ov2 > v || (ov2 == v && on < n)) { v = ov2; n = on; }
        }
        tv[r] = v; tn[r] = n;
        bool mine = (n & 63) == lane;
        int  kk = n >> 6;
        v0 = (mine && kk == 0) ? -2e9f : v0;
        v1 = (mine && kk == 1) ? -2e9f : v1;
        v2 = (mine && kk == 2) ? -2e9f : v2;
    }

    // softmax weights + neighbor global indices (uniform across wave)
    float wts[TOPK]; int qn[TOPK];
    float wsum = 0.f;
    #pragma unroll
    for (int r = 0; r < TOPK; ++r) {
        float e = expf(tv[r] - tv[0]);
        wts[r] = e; wsum += e;
        int n  = tn[r];
        int dy = n / WIN - HALF;
        int dx = n - (dy + HALF) * WIN - HALF;
        int gy = min(max(py + dy, 0), HH - 1);
        int gx = min(max(px + dx, 0), WW - 1);
        qn[r]  = b * HWPIX + gy * WW + gx;
    }
    float winv = 1.0f / wsum;

    // own raw row + wave-reduced LN stats
    const float* xrow = xt + gp * CH;
    float r1  = xrow[lane];
    float r2v = xrow[64 + (lane & 31)];
    float r2  = (lane < 32) ? r2v : 0.f;
    float s  = r1 + r2;
    float ss = r1 * r1 + r2 * r2;
    #pragma unroll
    for (int off = 1; off < 64; off <<= 1) {
        s  += __shfl_xor(s, off);
        ss += __shfl_xor(ss, off);
    }
    float mu  = s * (1.0f / 96.0f);
    float var = ss * (1.0f / 96.0f) - mu * mu;
    float rsd = rsqrtf(var + 1e-5f);

    float a1 = 0.f, a2 = 0.f;
    #pragma unroll
    for (int r = 0; r < TOPK; ++r) {
        const float* qrow = xt + qn[r] * CH;
        a1 += wts[r] * qrow[lane];
        a2 += wts[r] * qrow[64 + (lane & 31)];
    }
    a1 *= winv; a2 *= winv;

    enh[gp * CH + lane] = a1 + (r1 - mu) * rsd * lnw[lane] + lnb[lane];
    if (lane < 32) {
        int c = 64 + lane;
        enh[gp * CH + c] = a2 + (r2 - mu) * rsd * lnw[c] + lnb[c];
    }
}

// ---------------------------------------------------------------------------
// K3: fused FFN. 8 px per block, 1152 blocks, 256 threads.
// ---------------------------------------------------------------------------
__global__ __launch_bounds__(256) void k3_ffn(
    const float* __restrict__ enh, const float* __restrict__ w1,
    const float* __restrict__ b1, const float* __restrict__ w2,
    const float* __restrict__ b2, float* __restrict__ out)
{
    __shared__ float hl[8][200];    // 6.25 KB, rows 800 B (16B-aligned)
    int g    = blockIdx.x;          // 1152 = 4 batches * 288 tiles
    int b    = g / 288;
    int p0   = (g % 288) * 8;
    int t    = threadIdx.x;
    int wv   = t >> 6;
    int lane = t & 63;
    int pix  = lane & 7;
    int sub  = lane >> 3;           // 0..7
    int grp  = wv * 8 + sub;        // 0..31
    int gp   = b * HWPIX + p0 + pix;

    float4 ereg[24];
    const float4* ev = (const float4*)(enh + gp * CH);
    #pragma unroll
    for (int c4 = 0; c4 < 24; ++c4) ereg[c4] = ev[c4];

    // phase A: 6 hidden units per lane
    const float4* w1v = (const float4*)w1;
    #pragma unroll
    for (int jj = 0; jj < 6; ++jj) {
        int j = grp * 6 + jj;
        float ax = 0.f, ay = 0.f, az = 0.f, aw = 0.f;
        #pragma unroll
        for (int c4 = 0; c4 < 24; ++c4) {
            float4 w4 = w1v[j * 24 + c4];
            ax += ereg[c4].x * w4.x; ay += ereg[c4].y * w4.y;
            az += ereg[c4].z * w4.z; aw += ereg[c4].w * w4.w;
        }
        hl[pix][j] = fmaxf(((ax + ay) + (az + aw)) + b1[j], 0.f);
    }
    __syncthreads();

    // phase B: 3 output channels per lane
    const float4* w2v = (const float4*)w2;
    const float4* hv4 = (const float4*)(&hl[pix][0]);
    float a0 = 0.f, a1 = 0.f, a2 = 0.f;
    int c0 = grp * 3;
    #pragma unroll 6
    for (int j4 = 0; j4 < 48; ++j4) {
        float4 hv = hv4[j4];
        float4 q0 = w2v[(c0 + 0) * 48 + j4];
        float4 q1 = w2v[(c0 + 1) * 48 + j4];
        float4 q2 = w2v[(c0 + 2) * 48 + j4];
        a0 += hv.x*q0.x + hv.y*q0.y + hv.z*q0.z + hv.w*q0.w;
        a1 += hv.x*q1.x + hv.y*q1.y + hv.z*q1.z + hv.w*q1.w;
        a2 += hv.x*q2.x + hv.y*q2.y + hv.z*q2.z + hv.w*q2.w;
    }

    float accs[3] = {a0, a1, a2};
    #pragma unroll
    for (int cc = 0; cc < 3; ++cc) {
        int c = c0 + cc;
        out[(b * CH + c) * HWPIX + p0 + pix] =
            enh[gp * CH + c] + accs[cc] + b2[c];
    }
}

// ---------------------------------------------------------------------------
extern "C" void kernel_launch(void* const* d_in, const int* in_sizes, int n_in,
                              void* d_out, int out_size, void* d_ws, size_t ws_size,
                              hipStream_t stream)
{
    const float* x   = (const float*)d_in[0];
    const float* w1  = (const float*)d_in[1];
    const float* b1  = (const float*)d_in[2];
    const float* w2  = (const float*)d_in[3];
    const float* b2  = (const float*)d_in[4];
    const float* lnw = (const float*)d_in[5];
    const float* lnb = (const float*)d_in[6];
    float* out = (float*)d_out;

    // xt lives in d_out (exactly NPIX*CH floats): k1 writes it, k2 consumes it,
    // k3 then overwrites d_out with the final output (stream-ordered).
    float* xt = out;

    // workspace: enh + invn = 893,952 floats = 3.58 MB
    float* ws   = (float*)d_ws;
    float* enh  = ws;                        // NPIX*96
    float* invn = enh + NPIX * CH;           // NPIX

    hipLaunchKernelGGL(k1_prep, dim3(288), dim3(256), 0, stream,
                       x, xt, invn);
    hipLaunchKernelGGL(k2_knn, dim3(NPIX / 4), dim3(256), 0, stream,
                       xt, invn, lnw, lnb, enh);
    hipLaunchKernelGGL(k3_ffn, dim3(1152), dim3(256), 0, stream,
                       enh, w1, b1, w2, b2, out);
}